// Round 1
// baseline (947.006 us; speedup 1.0000x reference)
//
#include <hip/hip_runtime.h>
#include <hip/hip_bf16.h>

#define B_   8
#define C_   512
#define N_   4096
#define G_   32
#define CPG  16
#define EPSV 1e-6f

typedef short s16x8 __attribute__((ext_vector_type(8)));
typedef float f32x4 __attribute__((ext_vector_type(4)));

__device__ __forceinline__ unsigned short f2bf(float f) {
    unsigned u = __builtin_bit_cast(unsigned, f);
    u += 0x7fffu + ((u >> 16) & 1u);
    return (unsigned short)(u >> 16);
}

// ---------------------------------------------------------------- kernel 1
// one block per (b,g): reduce 16*4096 contiguous floats
__global__ __launch_bounds__(256) void gn_stats_k(const float* __restrict__ x,
                                                  float* __restrict__ stats) {
    int blk = blockIdx.x;  // b*32+g
    const float4* p = (const float4*)(x + (size_t)blk * (CPG * N_));
    float s = 0.f, ss = 0.f;
    for (int i = threadIdx.x; i < (CPG * N_) / 4; i += 256) {
        float4 v = p[i];
        s  += v.x + v.y + v.z + v.w;
        ss += v.x * v.x + v.y * v.y + v.z * v.z + v.w * v.w;
    }
    for (int off = 32; off > 0; off >>= 1) {
        s  += __shfl_down(s, off);
        ss += __shfl_down(ss, off);
    }
    __shared__ float r0[4], r1[4];
    int wid = threadIdx.x >> 6;
    if ((threadIdx.x & 63) == 0) { r0[wid] = s; r1[wid] = ss; }
    __syncthreads();
    if (threadIdx.x == 0) {
        s  = r0[0] + r0[1] + r0[2] + r0[3];
        ss = r1[0] + r1[1] + r1[2] + r1[3];
        const float inv = 1.0f / (CPG * N_);
        float mean = s * inv;
        float var  = ss * inv - mean * mean;
        stats[2 * blk]     = mean;
        stats[2 * blk + 1] = rsqrtf(var + EPSV);
    }
}

// ---------------------------------------------------------------- kernel 2
// convert wq|wk|wv (f32) -> bf16, concatenated
__global__ __launch_bounds__(256) void cvt_w_k(const float* __restrict__ wq,
                                               const float* __restrict__ wk,
                                               const float* __restrict__ wv,
                                               unsigned short* __restrict__ wbf) {
    int i = blockIdx.x * 256 + threadIdx.x;   // float4 index, total 3*C*C/4
    const int percc = C_ * C_ / 4;
    const float* src; int li;
    if (i < percc)            { src = wq; li = i; }
    else if (i < 2 * percc)   { src = wk; li = i - percc; }
    else                      { src = wv; li = i - 2 * percc; }
    float4 v = ((const float4*)src)[li];
    unsigned u0 = (unsigned)f2bf(v.x) | ((unsigned)f2bf(v.y) << 16);
    unsigned u1 = (unsigned)f2bf(v.z) | ((unsigned)f2bf(v.w) << 16);
    uint2 o; o.x = u0; o.y = u1;
    *(uint2*)&wbf[(size_t)i * 4] = o;
}

// ---------------------------------------------------------------- kernel 3
// group-norm apply + transpose: x[b][c][n] f32 -> h_t[b][n][c] bf16
__global__ __launch_bounds__(256) void gn_apply_k(const float* __restrict__ x,
                                                  const float* __restrict__ stats,
                                                  const float* __restrict__ gsc,
                                                  const float* __restrict__ gbi,
                                                  unsigned short* __restrict__ h_t) {
    int nt = blockIdx.x, ct = blockIdx.y, b = blockIdx.z;
    int n0 = nt * 64, c0 = ct * 64;
    __shared__ unsigned short T[64][72];   // [n][c], padded (144B rows, 16B aligned)
    int t = threadIdx.x;
    int cl = t >> 2, ch = t & 3;
    int c = c0 + cl;
    int g = c >> 4;
    float mean = stats[(b * G_ + g) * 2];
    float rstd = stats[(b * G_ + g) * 2 + 1];
    float sc = gsc[c] * rstd;
    float bi = gbi[c] - mean * sc;   // y = x*sc + bi
    const float* xr = x + (size_t)(b * C_ + c) * N_ + n0 + ch * 16;
    #pragma unroll
    for (int q = 0; q < 4; ++q) {
        float4 v = *(const float4*)(xr + q * 4);
        int nl = ch * 16 + q * 4;
        T[nl + 0][cl] = f2bf(fmaf(v.x, sc, bi));
        T[nl + 1][cl] = f2bf(fmaf(v.y, sc, bi));
        T[nl + 2][cl] = f2bf(fmaf(v.z, sc, bi));
        T[nl + 3][cl] = f2bf(fmaf(v.w, sc, bi));
    }
    __syncthreads();
    #pragma unroll
    for (int it = 0; it < 2; ++it) {
        int id = t + it * 256;
        int nl = id >> 3, part = id & 7;
        s16x8 val = *(const s16x8*)&T[nl][part * 8];
        *(s16x8*)&h_t[((size_t)b * N_ + n0 + nl) * C_ + c0 + part * 8] = val;
    }
}

// ---------------------------------------------------------------- kernel 4
// generic C[M][N] = A[M][:] . B[N][:]^T  (both row-major, K=512 contig) + bias
// which 0/1 (q/k): A=h_t[b], B=wq/wk, C=q_t/k_t [n][o], bias over cols
// which 2   (v)  : A=wv,     B=h_t[b], C=v [o][n],      bias over rows
__global__ __launch_bounds__(256) void qkv_k(const unsigned short* __restrict__ h_t,
                                             const unsigned short* __restrict__ wbf,
                                             const float* __restrict__ bq,
                                             const float* __restrict__ bk,
                                             const float* __restrict__ bv,
                                             unsigned short* __restrict__ q_t,
                                             unsigned short* __restrict__ k_t,
                                             unsigned short* __restrict__ vv) {
    int which = blockIdx.z % 3;
    int b     = blockIdx.z / 3;
    int bx = blockIdx.x, by = blockIdx.y;   // grid (32,4,24)
    const unsigned short* A;
    const unsigned short* Bm;
    unsigned short* Cm;
    const float* bias;
    int m0, n0; size_t ldc; bool biasRow;
    const unsigned short* hb = h_t + (size_t)b * N_ * C_;
    if (which < 2) {
        A = hb; Bm = wbf + (size_t)which * C_ * C_;
        Cm = (which == 0 ? q_t : k_t) + (size_t)b * N_ * C_;
        bias = (which == 0 ? bq : bk);
        m0 = bx * 128; n0 = by * 128; ldc = C_; biasRow = false;
    } else {
        A = wbf + (size_t)2 * C_ * C_; Bm = hb;
        Cm = vv + (size_t)b * C_ * N_;
        bias = bv;
        m0 = by * 128; n0 = bx * 128; ldc = N_; biasRow = true;
    }

    __shared__ char smem[34816];
    unsigned short* Al = (unsigned short*)smem;        // [128][40]
    unsigned short* Bl = Al + 128 * 40;                // [128][40]
    unsigned short* El = (unsigned short*)smem;        // [128][136] epilogue alias

    int t = threadIdx.x;
    int wid = t >> 6, lane = t & 63;
    int wm = (wid >> 1) * 64, wn = (wid & 1) * 64;
    int lr = lane & 15, lg = lane >> 4;

    f32x4 acc[4][4] = {};
    for (int k0 = 0; k0 < C_; k0 += 32) {
        __syncthreads();
        #pragma unroll
        for (int it = 0; it < 2; ++it) {
            int id = t + it * 256;
            int row = id >> 2, ch = id & 3;
            *(s16x8*)&Al[row * 40 + ch * 8] =
                *(const s16x8*)&A[(size_t)(m0 + row) * C_ + k0 + ch * 8];
            *(s16x8*)&Bl[row * 40 + ch * 8] =
                *(const s16x8*)&Bm[(size_t)(n0 + row) * C_ + k0 + ch * 8];
        }
        __syncthreads();
        s16x8 a[4], bb[4];
        #pragma unroll
        for (int i = 0; i < 4; ++i) a[i]  = *(const s16x8*)&Al[(wm + i * 16 + lr) * 40 + lg * 8];
        #pragma unroll
        for (int j = 0; j < 4; ++j) bb[j] = *(const s16x8*)&Bl[(wn + j * 16 + lr) * 40 + lg * 8];
        #pragma unroll
        for (int i = 0; i < 4; ++i)
            #pragma unroll
            for (int j = 0; j < 4; ++j)
                acc[i][j] = __builtin_amdgcn_mfma_f32_16x16x32_bf16(a[i], bb[j], acc[i][j], 0, 0, 0);
    }

    // epilogue: bias + bf16 + LDS transpose for coalesced store
    float rb[4][4], cb[4];
    #pragma unroll
    for (int i = 0; i < 4; ++i)
        #pragma unroll
        for (int r = 0; r < 4; ++r)
            rb[i][r] = biasRow ? bias[m0 + wm + i * 16 + lg * 4 + r] : 0.f;
    #pragma unroll
    for (int j = 0; j < 4; ++j)
        cb[j] = biasRow ? 0.f : bias[n0 + wn + j * 16 + lr];

    __syncthreads();
    #pragma unroll
    for (int i = 0; i < 4; ++i)
        #pragma unroll
        for (int j = 0; j < 4; ++j) {
            int col = wn + j * 16 + lr;
            #pragma unroll
            for (int r = 0; r < 4; ++r) {
                int row = wm + i * 16 + lg * 4 + r;
                El[row * 136 + col] = f2bf(acc[i][j][r] + rb[i][r] + cb[j]);
            }
        }
    __syncthreads();
    #pragma unroll
    for (int it = 0; it < 8; ++it) {
        int id = t + it * 256;
        int row = id >> 4, part = id & 15;
        *(s16x8*)&Cm[(size_t)(m0 + row) * ldc + n0 + part * 8] =
            *(const s16x8*)&El[row * 136 + part * 8];
    }
}

// ---------------------------------------------------------------- kernel 5
// flash attention: block = (b, 64-row i-tile), 8 waves.
// QK split: wave w -> rows (w>>1)*16, col-half (w&1)*32. PV split: wave w -> c-slice w*64.
__global__ __launch_bounds__(512) void attn_k(const unsigned short* __restrict__ q_t,
                                              const unsigned short* __restrict__ k_t,
                                              const unsigned short* __restrict__ vv,
                                              const float* __restrict__ x,
                                              float* __restrict__ out) {
    int itile = blockIdx.x, b = blockIdx.y;
    int i0 = itile * 64;
    const unsigned short* qb = q_t + (size_t)b * N_ * C_;
    const unsigned short* kb = k_t + (size_t)b * N_ * C_;
    const unsigned short* vb = vv + (size_t)b * C_ * N_;
    const float* xb = x + (size_t)b * C_ * N_;
    float* ob = out + (size_t)b * C_ * N_;

    __shared__ unsigned short Kl[64 * 512];  // 64KB, XOR-swizzled rows
    __shared__ unsigned short Pl[64][72];    // P bf16, padded
    __shared__ float pm[2][64], ps[2][64], rsl[64], lfl[64];

    int t = threadIdx.x;
    int wid = t >> 6, lane = t & 63;
    int fi = wid >> 1, half = wid & 1;
    int lr = lane & 15, lg = lane >> 4;

    // Q fragments in registers: rows i0+fi*16+lr, k = kc*32 + lg*8
    s16x8 qf[16];
    {
        const unsigned short* qrow = qb + (size_t)(i0 + fi * 16 + lr) * C_ + lg * 8;
        #pragma unroll
        for (int kc = 0; kc < 16; ++kc) qf[kc] = *(const s16x8*)(qrow + kc * 32);
    }

    f32x4 accO[4][4] = {};
    float m_r[4], l_r[4];
    #pragma unroll
    for (int r = 0; r < 4; ++r) { m_r[r] = -1e30f; l_r[r] = 0.f; }

    const float SCL = 0.0441941738f * 1.4426950408889634f;  // C^-0.5 * log2(e)

    for (int jt = 0; jt < 64; ++jt) {
        int j0 = jt * 64;
        // ---- stage K tile [64 j][512 c] bf16, swizzled (8 x 16B per thread)
        #pragma unroll
        for (int s = 0; s < 8; ++s) {
            int id = t + s * 512;
            int row = id >> 6, cp = id & 63;
            unsigned addr = (unsigned)(row * 1024 + cp * 16);
            addr ^= (unsigned)((row & 7) << 4);
            *(s16x8*)((char*)Kl + addr) = *(const s16x8*)&kb[(size_t)(j0 + row) * C_ + cp * 8];
        }
        __syncthreads();

        // ---- QK^T
        f32x4 accS[2] = {};
        #pragma unroll
        for (int kc = 0; kc < 16; ++kc) {
            #pragma unroll
            for (int fj = 0; fj < 2; ++fj) {
                int j = half * 32 + fj * 16 + lr;
                unsigned addr = (unsigned)(j * 1024 + kc * 64 + lg * 16);
                addr ^= (unsigned)((j & 7) << 4);
                s16x8 kf = *(const s16x8*)((const char*)Kl + addr);
                accS[fj] = __builtin_amdgcn_mfma_f32_16x16x32_bf16(qf[kc], kf, accS[fj], 0, 0, 0);
            }
        }
        // scale (folded log2e) + per-wave row max over its 32 cols
        float pmax[4];
        #pragma unroll
        for (int r = 0; r < 4; ++r) {
            accS[0][r] *= SCL; accS[1][r] *= SCL;
            pmax[r] = fmaxf(accS[0][r], accS[1][r]);
        }
        #pragma unroll
        for (int msk = 8; msk >= 1; msk >>= 1)
            #pragma unroll
            for (int r = 0; r < 4; ++r)
                pmax[r] = fmaxf(pmax[r], __shfl_xor(pmax[r], msk));
        if (lr == 0) {
            #pragma unroll
            for (int r = 0; r < 4; ++r) pm[half][fi * 16 + lg * 4 + r] = pmax[r];
        }
        __syncthreads();

        // ---- softmax: new max, P=exp2(s-m), partial sums
        float rs[4], psum[4];
        #pragma unroll
        for (int r = 0; r < 4; ++r) {
            int row = fi * 16 + lg * 4 + r;
            float mn = fmaxf(m_r[r], fmaxf(pm[0][row], pm[1][row]));
            rs[r] = exp2f(m_r[r] - mn);
            float p0 = exp2f(accS[0][r] - mn);
            float p1 = exp2f(accS[1][r] - mn);
            Pl[row][half * 32 + lr]      = f2bf(p0);
            Pl[row][half * 32 + 16 + lr] = f2bf(p1);
            psum[r] = p0 + p1;
            m_r[r] = mn;
        }
        #pragma unroll
        for (int msk = 8; msk >= 1; msk >>= 1)
            #pragma unroll
            for (int r = 0; r < 4; ++r) psum[r] += __shfl_xor(psum[r], msk);
        if (lr == 0) {
            #pragma unroll
            for (int r = 0; r < 4; ++r) {
                int row = fi * 16 + lg * 4 + r;
                ps[half][row] = psum[r];
                if (half == 0) rsl[row] = rs[r];
            }
        }
        __syncthreads();

        // ---- l update + O rescale + PV
        #pragma unroll
        for (int r = 0; r < 4; ++r) {
            int row = fi * 16 + lg * 4 + r;
            l_r[r] = l_r[r] * rs[r] + ps[0][row] + ps[1][row];
        }
        #pragma unroll
        for (int f2 = 0; f2 < 4; ++f2)
            #pragma unroll
            for (int r = 0; r < 4; ++r) {
                float f = rsl[f2 * 16 + lg * 4 + r];
                #pragma unroll
                for (int fc = 0; fc < 4; ++fc) accO[f2][fc][r] *= f;
            }
        #pragma unroll
        for (int ks = 0; ks < 2; ++ks) {
            s16x8 vf[4];
            #pragma unroll
            for (int fc = 0; fc < 4; ++fc) {
                int c = wid * 64 + fc * 16 + lr;
                vf[fc] = *(const s16x8*)&vb[(size_t)c * N_ + j0 + ks * 32 + lg * 8];
            }
            #pragma unroll
            for (int f2 = 0; f2 < 4; ++f2) {
                s16x8 pf = *(const s16x8*)&Pl[f2 * 16 + lr][ks * 32 + lg * 8];
                #pragma unroll
                for (int fc = 0; fc < 4; ++fc)
                    accO[f2][fc] = __builtin_amdgcn_mfma_f32_16x16x32_bf16(pf, vf[fc], accO[f2][fc], 0, 0, 0);
            }
        }
        // no barrier needed here: next-iter K staging touches a region whose last
        // reads (QK) completed before the pm barrier above.
    }

    // ---- epilogue: out = x + O / l
    if (half == 0 && lr == 0) {
        #pragma unroll
        for (int r = 0; r < 4; ++r) lfl[fi * 16 + lg * 4 + r] = l_r[r];
    }
    __syncthreads();
    #pragma unroll
    for (int f2 = 0; f2 < 4; ++f2) {
        float rinv[4];
        #pragma unroll
        for (int r = 0; r < 4; ++r) rinv[r] = 1.0f / lfl[f2 * 16 + lg * 4 + r];
        #pragma unroll
        for (int fc = 0; fc < 4; ++fc) {
            int c = wid * 64 + fc * 16 + lr;
            size_t base = (size_t)c * N_ + i0 + f2 * 16 + lg * 4;
            float4 xv = *(const float4*)&xb[base];
            float4 o;
            o.x = xv.x + accO[f2][fc][0] * rinv[0];
            o.y = xv.y + accO[f2][fc][1] * rinv[1];
            o.z = xv.z + accO[f2][fc][2] * rinv[2];
            o.w = xv.w + accO[f2][fc][3] * rinv[3];
            *(float4*)&ob[base] = o;
        }
    }
}

// ---------------------------------------------------------------- launch
extern "C" void kernel_launch(void* const* d_in, const int* in_sizes, int n_in,
                              void* d_out, int out_size, void* d_ws, size_t ws_size,
                              hipStream_t stream) {
    const float* x   = (const float*)d_in[0];
    const float* gsc = (const float*)d_in[1];
    const float* gbi = (const float*)d_in[2];
    const float* wq  = (const float*)d_in[3];
    const float* bq  = (const float*)d_in[4];
    const float* wk  = (const float*)d_in[5];
    const float* bk  = (const float*)d_in[6];
    const float* wv  = (const float*)d_in[7];
    const float* bv  = (const float*)d_in[8];
    float* out = (float*)d_out;

    const size_t elems = (size_t)B_ * N_ * C_;          // 16,777,216
    // workspace: q_t | k_t | v (bf16, 32MB each) | stats | wbf  (~102.2 MB total)
    unsigned short* q_t   = (unsigned short*)d_ws;
    unsigned short* k_t   = q_t + elems;
    unsigned short* v     = k_t + elems;
    float*          stats = (float*)(v + elems);
    unsigned short* wbf   = (unsigned short*)(stats + 2 * B_ * G_);
    // h_t (bf16, 32MB) lives in d_out: dead before attn_k writes d_out.
    unsigned short* h_t   = (unsigned short*)d_out;

    gn_stats_k<<<B_ * G_, 256, 0, stream>>>(x, stats);
    cvt_w_k<<<(3 * C_ * C_ / 4) / 256, 256, 0, stream>>>(wq, wk, wv, wbf);
    gn_apply_k<<<dim3(N_ / 64, C_ / 64, B_), 256, 0, stream>>>(x, stats, gsc, gbi, h_t);
    qkv_k<<<dim3(32, 4, 3 * B_), 256, 0, stream>>>(h_t, wbf, bq, bk, bv, q_t, k_t, v);
    attn_k<<<dim3(N_ / 64, B_), 512, 0, stream>>>(q_t, k_t, v, x, out);
}

// Round 2
// 853.821 us; speedup vs baseline: 1.1091x; 1.1091x over previous
//
#include <hip/hip_runtime.h>
#include <hip/hip_bf16.h>

#define B_   8
#define C_   512
#define N_   4096
#define G_   32
#define CPG  16
#define EPSV 1e-6f

typedef short s16x8 __attribute__((ext_vector_type(8)));
typedef float f32x4 __attribute__((ext_vector_type(4)));

__device__ __forceinline__ unsigned short f2bf(float f) {
    unsigned u = __builtin_bit_cast(unsigned, f);
    u += 0x7fffu + ((u >> 16) & 1u);
    return (unsigned short)(u >> 16);
}

__device__ __forceinline__ void gload_lds16(const unsigned short* g, unsigned short* l) {
    __builtin_amdgcn_global_load_lds((const __attribute__((address_space(1))) void*)g,
                                     (__attribute__((address_space(3))) void*)l, 16, 0, 0);
}

// ---------------------------------------------------------------- kernel 1
__global__ __launch_bounds__(256) void gn_stats_k(const float* __restrict__ x,
                                                  float* __restrict__ stats) {
    int blk = blockIdx.x;  // b*32+g
    const float4* p = (const float4*)(x + (size_t)blk * (CPG * N_));
    float s = 0.f, ss = 0.f;
    for (int i = threadIdx.x; i < (CPG * N_) / 4; i += 256) {
        float4 v = p[i];
        s  += v.x + v.y + v.z + v.w;
        ss += v.x * v.x + v.y * v.y + v.z * v.z + v.w * v.w;
    }
    for (int off = 32; off > 0; off >>= 1) {
        s  += __shfl_down(s, off);
        ss += __shfl_down(ss, off);
    }
    __shared__ float r0[4], r1[4];
    int wid = threadIdx.x >> 6;
    if ((threadIdx.x & 63) == 0) { r0[wid] = s; r1[wid] = ss; }
    __syncthreads();
    if (threadIdx.x == 0) {
        s  = r0[0] + r0[1] + r0[2] + r0[3];
        ss = r1[0] + r1[1] + r1[2] + r1[3];
        const float inv = 1.0f / (CPG * N_);
        float mean = s * inv;
        float var  = ss * inv - mean * mean;
        stats[2 * blk]     = mean;
        stats[2 * blk + 1] = rsqrtf(var + EPSV);
    }
}

// ---------------------------------------------------------------- kernel 2
__global__ __launch_bounds__(256) void cvt_w_k(const float* __restrict__ wq,
                                               const float* __restrict__ wk,
                                               const float* __restrict__ wv,
                                               unsigned short* __restrict__ wbf) {
    int i = blockIdx.x * 256 + threadIdx.x;
    const int percc = C_ * C_ / 4;
    const float* src; int li;
    if (i < percc)            { src = wq; li = i; }
    else if (i < 2 * percc)   { src = wk; li = i - percc; }
    else                      { src = wv; li = i - 2 * percc; }
    float4 v = ((const float4*)src)[li];
    unsigned u0 = (unsigned)f2bf(v.x) | ((unsigned)f2bf(v.y) << 16);
    unsigned u1 = (unsigned)f2bf(v.z) | ((unsigned)f2bf(v.w) << 16);
    uint2 o; o.x = u0; o.y = u1;
    *(uint2*)&wbf[(size_t)i * 4] = o;
}

// ---------------------------------------------------------------- kernel 3
__global__ __launch_bounds__(256) void gn_apply_k(const float* __restrict__ x,
                                                  const float* __restrict__ stats,
                                                  const float* __restrict__ gsc,
                                                  const float* __restrict__ gbi,
                                                  unsigned short* __restrict__ h_t) {
    int nt = blockIdx.x, ct = blockIdx.y, b = blockIdx.z;
    int n0 = nt * 64, c0 = ct * 64;
    __shared__ unsigned short T[64][72];
    int t = threadIdx.x;
    int cl = t >> 2, ch = t & 3;
    int c = c0 + cl;
    int g = c >> 4;
    float mean = stats[(b * G_ + g) * 2];
    float rstd = stats[(b * G_ + g) * 2 + 1];
    float sc = gsc[c] * rstd;
    float bi = gbi[c] - mean * sc;
    const float* xr = x + (size_t)(b * C_ + c) * N_ + n0 + ch * 16;
    #pragma unroll
    for (int q = 0; q < 4; ++q) {
        float4 v = *(const float4*)(xr + q * 4);
        int nl = ch * 16 + q * 4;
        T[nl + 0][cl] = f2bf(fmaf(v.x, sc, bi));
        T[nl + 1][cl] = f2bf(fmaf(v.y, sc, bi));
        T[nl + 2][cl] = f2bf(fmaf(v.z, sc, bi));
        T[nl + 3][cl] = f2bf(fmaf(v.w, sc, bi));
    }
    __syncthreads();
    #pragma unroll
    for (int it = 0; it < 2; ++it) {
        int id = t + it * 256;
        int nl = id >> 3, part = id & 7;
        s16x8 val = *(const s16x8*)&T[nl][part * 8];
        *(s16x8*)&h_t[((size_t)b * N_ + n0 + nl) * C_ + c0 + part * 8] = val;
    }
}

// ---------------------------------------------------------------- kernel 4
__global__ __launch_bounds__(256) void qkv_k(const unsigned short* __restrict__ h_t,
                                             const unsigned short* __restrict__ wbf,
                                             const float* __restrict__ bq,
                                             const float* __restrict__ bk,
                                             const float* __restrict__ bv,
                                             unsigned short* __restrict__ q_t,
                                             unsigned short* __restrict__ k_t,
                                             unsigned short* __restrict__ vv) {
    int which = blockIdx.z % 3;
    int b     = blockIdx.z / 3;
    int bx = blockIdx.x, by = blockIdx.y;
    const unsigned short* A;
    const unsigned short* Bm;
    unsigned short* Cm;
    const float* bias;
    int m0, n0; size_t ldc; bool biasRow;
    const unsigned short* hb = h_t + (size_t)b * N_ * C_;
    if (which < 2) {
        A = hb; Bm = wbf + (size_t)which * C_ * C_;
        Cm = (which == 0 ? q_t : k_t) + (size_t)b * N_ * C_;
        bias = (which == 0 ? bq : bk);
        m0 = bx * 128; n0 = by * 128; ldc = C_; biasRow = false;
    } else {
        A = wbf + (size_t)2 * C_ * C_; Bm = hb;
        Cm = vv + (size_t)b * C_ * N_;
        bias = bv;
        m0 = by * 128; n0 = bx * 128; ldc = N_; biasRow = true;
    }

    __shared__ char smem[34816];
    unsigned short* Al = (unsigned short*)smem;
    unsigned short* Bl = Al + 128 * 40;
    unsigned short* El = (unsigned short*)smem;

    int t = threadIdx.x;
    int wid = t >> 6, lane = t & 63;
    int wm = (wid >> 1) * 64, wn = (wid & 1) * 64;
    int lr = lane & 15, lg = lane >> 4;

    f32x4 acc[4][4] = {};
    for (int k0 = 0; k0 < C_; k0 += 32) {
        __syncthreads();
        #pragma unroll
        for (int it = 0; it < 2; ++it) {
            int id = t + it * 256;
            int row = id >> 2, ch = id & 3;
            *(s16x8*)&Al[row * 40 + ch * 8] =
                *(const s16x8*)&A[(size_t)(m0 + row) * C_ + k0 + ch * 8];
            *(s16x8*)&Bl[row * 40 + ch * 8] =
                *(const s16x8*)&Bm[(size_t)(n0 + row) * C_ + k0 + ch * 8];
        }
        __syncthreads();
        s16x8 a[4], bb[4];
        #pragma unroll
        for (int i = 0; i < 4; ++i) a[i]  = *(const s16x8*)&Al[(wm + i * 16 + lr) * 40 + lg * 8];
        #pragma unroll
        for (int j = 0; j < 4; ++j) bb[j] = *(const s16x8*)&Bl[(wn + j * 16 + lr) * 40 + lg * 8];
        #pragma unroll
        for (int i = 0; i < 4; ++i)
            #pragma unroll
            for (int j = 0; j < 4; ++j)
                acc[i][j] = __builtin_amdgcn_mfma_f32_16x16x32_bf16(a[i], bb[j], acc[i][j], 0, 0, 0);
    }

    float rb[4][4], cb[4];
    #pragma unroll
    for (int i = 0; i < 4; ++i)
        #pragma unroll
        for (int r = 0; r < 4; ++r)
            rb[i][r] = biasRow ? bias[m0 + wm + i * 16 + lg * 4 + r] : 0.f;
    #pragma unroll
    for (int j = 0; j < 4; ++j)
        cb[j] = biasRow ? 0.f : bias[n0 + wn + j * 16 + lr];

    __syncthreads();
    #pragma unroll
    for (int i = 0; i < 4; ++i)
        #pragma unroll
        for (int j = 0; j < 4; ++j) {
            int col = wn + j * 16 + lr;
            #pragma unroll
            for (int r = 0; r < 4; ++r) {
                int row = wm + i * 16 + lg * 4 + r;
                El[row * 136 + col] = f2bf(acc[i][j][r] + rb[i][r] + cb[j]);
            }
        }
    __syncthreads();
    #pragma unroll
    for (int it = 0; it < 8; ++it) {
        int id = t + it * 256;
        int row = id >> 4, part = id & 15;
        *(s16x8*)&Cm[(size_t)(m0 + row) * ldc + n0 + part * 8] =
            *(const s16x8*)&El[row * 136 + part * 8];
    }
}

// ---------------------------------------------------------------- kernel 5
// flash attention, i-tile 128, 8 waves x 16 own rows.
// Per jt: [stage K[nxt] async] QK (full 64 keys, own rows) -> in-wave softmax ->
// P to LDS -> barrier -> rescale+PV (c-split 64/wave, V from global) -> barrier.
__global__ __launch_bounds__(512, 2) void attn_k(const unsigned short* __restrict__ q_t,
                                                 const unsigned short* __restrict__ k_t,
                                                 const unsigned short* __restrict__ vv,
                                                 const float* __restrict__ x,
                                                 float* __restrict__ out) {
    int i0 = blockIdx.x * 128;
    int b  = blockIdx.y;
    const unsigned short* qb = q_t + (size_t)b * N_ * C_;
    const unsigned short* kb = k_t + (size_t)b * N_ * C_;
    const unsigned short* vb = vv + (size_t)b * C_ * N_;
    const float* xb = x + (size_t)b * C_ * N_;
    float* ob = out + (size_t)b * C_ * N_;

    __shared__ unsigned short Kl[2][64 * 512];  // 2 x 64KB, swizzled content
    __shared__ unsigned short Pl[128][72];      // 18KB, row stride 144B
    __shared__ float rsl[128];
    __shared__ float lfl[128];

    int t = threadIdx.x;
    int wid = t >> 6, lane = t & 63;
    int lr = lane & 15, lg = lane >> 4;
    int sw = lr & 7;

    // stage helper: linear LDS dest + inverse-swizzled global source (rule #21)
    auto stage = [&](unsigned short* dst, int j0) {
        #pragma unroll
        for (int s = 0; s < 8; ++s) {
            int id = t + s * 512;
            int row = id >> 6, cp = id & 63;
            int cps = cp ^ (row & 7);
            gload_lds16(&kb[(size_t)(j0 + row) * C_ + cps * 8], &dst[row * 512 + cp * 8]);
        }
    };

    // Q fragments: rows i0 + wid*16 + lr, k = kc*32 + lg*8
    s16x8 qf[16];
    {
        const unsigned short* qrow = qb + (size_t)(i0 + wid * 16 + lr) * C_ + lg * 8;
        #pragma unroll
        for (int kc = 0; kc < 16; ++kc) qf[kc] = *(const s16x8*)(qrow + kc * 32);
    }

    f32x4 accO[8][4] = {};
    float m_r[4], l_r[4];
    #pragma unroll
    for (int r = 0; r < 4; ++r) { m_r[r] = -1e30f; l_r[r] = 0.f; }

    const float SCL = 0.0441941738f * 1.4426950408889634f;  // C^-0.5 * log2(e)

    stage(&Kl[0][0], 0);
    __syncthreads();
    int cur = 0;

    for (int jt = 0; jt < 64; ++jt) {
        int j0 = jt * 64;
        if (jt < 63) stage(&Kl[cur ^ 1][0], j0 + 64);

        // ---- QK^T: own 16 rows x 64 keys, full K=512
        const unsigned short* Kc = &Kl[cur][0];
        f32x4 accS[4] = {};
        #pragma unroll
        for (int kc = 0; kc < 16; ++kc) {
            #pragma unroll
            for (int fj = 0; fj < 4; ++fj) {
                int row = fj * 16 + lr;
                int cp = (kc * 4 + lg) ^ sw;
                s16x8 kf = *(const s16x8*)&Kc[row * 512 + cp * 8];
                accS[fj] = __builtin_amdgcn_mfma_f32_16x16x32_bf16(qf[kc], kf, accS[fj], 0, 0, 0);
            }
        }

        // ---- in-wave softmax (rows lg*4+r spread over lr lanes x 4 frags)
        float mx[4];
        #pragma unroll
        for (int r = 0; r < 4; ++r) {
            #pragma unroll
            for (int fj = 0; fj < 4; ++fj) accS[fj][r] *= SCL;
            mx[r] = fmaxf(fmaxf(accS[0][r], accS[1][r]), fmaxf(accS[2][r], accS[3][r]));
        }
        #pragma unroll
        for (int msk = 8; msk >= 1; msk >>= 1)
            #pragma unroll
            for (int r = 0; r < 4; ++r) mx[r] = fmaxf(mx[r], __shfl_xor(mx[r], msk));

        float rs[4], psum[4];
        #pragma unroll
        for (int r = 0; r < 4; ++r) {
            float mn = fmaxf(m_r[r], mx[r]);
            rs[r] = exp2f(m_r[r] - mn);
            m_r[r] = mn;
            psum[r] = 0.f;
            int prow = wid * 16 + lg * 4 + r;
            #pragma unroll
            for (int fj = 0; fj < 4; ++fj) {
                float p = exp2f(accS[fj][r] - mn);
                Pl[prow][fj * 16 + lr] = f2bf(p);
                psum[r] += p;
            }
        }
        #pragma unroll
        for (int msk = 8; msk >= 1; msk >>= 1)
            #pragma unroll
            for (int r = 0; r < 4; ++r) psum[r] += __shfl_xor(psum[r], msk);
        #pragma unroll
        for (int r = 0; r < 4; ++r) l_r[r] = l_r[r] * rs[r] + psum[r];
        if (lr == 0) {
            #pragma unroll
            for (int r = 0; r < 4; ++r) rsl[wid * 16 + lg * 4 + r] = rs[r];
        }
        __syncthreads();  // P + rsl visible; stage drained

        // ---- rescale accO, then PV: own c-slice 64 x all 128 rows
        #pragma unroll
        for (int rb = 0; rb < 8; ++rb) {
            float4 rsf = *(const float4*)&rsl[rb * 16 + lg * 4];
            #pragma unroll
            for (int fc = 0; fc < 4; ++fc) {
                accO[rb][fc][0] *= rsf.x;
                accO[rb][fc][1] *= rsf.y;
                accO[rb][fc][2] *= rsf.z;
                accO[rb][fc][3] *= rsf.w;
            }
        }
        #pragma unroll
        for (int ks = 0; ks < 2; ++ks) {
            s16x8 vf[4];
            #pragma unroll
            for (int fc = 0; fc < 4; ++fc) {
                int c = wid * 64 + fc * 16 + lr;
                vf[fc] = *(const s16x8*)&vb[(size_t)c * N_ + j0 + ks * 32 + lg * 8];
            }
            #pragma unroll
            for (int rb = 0; rb < 8; ++rb) {
                s16x8 pf = *(const s16x8*)&Pl[rb * 16 + lr][ks * 32 + lg * 8];
                #pragma unroll
                for (int fc = 0; fc < 4; ++fc)
                    accO[rb][fc] = __builtin_amdgcn_mfma_f32_16x16x32_bf16(pf, vf[fc], accO[rb][fc], 0, 0, 0);
            }
        }
        __syncthreads();  // PV done before next jt's P write / K overwrite window
        cur ^= 1;
    }

    // ---- epilogue: out = x + O / l
    if (lr == 0) {
        #pragma unroll
        for (int r = 0; r < 4; ++r) lfl[wid * 16 + lg * 4 + r] = l_r[r];
    }
    __syncthreads();
    #pragma unroll
    for (int rb = 0; rb < 8; ++rb) {
        float4 lf = *(const float4*)&lfl[rb * 16 + lg * 4];
        float rinv[4] = {1.0f / lf.x, 1.0f / lf.y, 1.0f / lf.z, 1.0f / lf.w};
        #pragma unroll
        for (int fc = 0; fc < 4; ++fc) {
            int c = wid * 64 + fc * 16 + lr;
            size_t base = (size_t)c * N_ + i0 + rb * 16 + lg * 4;
            float4 xv = *(const float4*)&xb[base];
            float4 o;
            o.x = xv.x + accO[rb][fc][0] * rinv[0];
            o.y = xv.y + accO[rb][fc][1] * rinv[1];
            o.z = xv.z + accO[rb][fc][2] * rinv[2];
            o.w = xv.w + accO[rb][fc][3] * rinv[3];
            *(float4*)&ob[base] = o;
        }
    }
}

// ---------------------------------------------------------------- launch
extern "C" void kernel_launch(void* const* d_in, const int* in_sizes, int n_in,
                              void* d_out, int out_size, void* d_ws, size_t ws_size,
                              hipStream_t stream) {
    const float* x   = (const float*)d_in[0];
    const float* gsc = (const float*)d_in[1];
    const float* gbi = (const float*)d_in[2];
    const float* wq  = (const float*)d_in[3];
    const float* bq  = (const float*)d_in[4];
    const float* wk  = (const float*)d_in[5];
    const float* bk  = (const float*)d_in[6];
    const float* wv  = (const float*)d_in[7];
    const float* bv  = (const float*)d_in[8];
    float* out = (float*)d_out;

    const size_t elems = (size_t)B_ * N_ * C_;
    unsigned short* q_t   = (unsigned short*)d_ws;
    unsigned short* k_t   = q_t + elems;
    unsigned short* v     = k_t + elems;
    float*          stats = (float*)(v + elems);
    unsigned short* wbf   = (unsigned short*)(stats + 2 * B_ * G_);
    unsigned short* h_t   = (unsigned short*)d_out;  // dead before attn writes

    gn_stats_k<<<B_ * G_, 256, 0, stream>>>(x, stats);
    cvt_w_k<<<(3 * C_ * C_ / 4) / 256, 256, 0, stream>>>(wq, wk, wv, wbf);
    gn_apply_k<<<dim3(N_ / 64, C_ / 64, B_), 256, 0, stream>>>(x, stats, gsc, gbi, h_t);
    qkv_k<<<dim3(32, 4, 3 * B_), 256, 0, stream>>>(h_t, wbf, bq, bk, bv, q_t, k_t, v);
    attn_k<<<dim3(N_ / 128, B_), 512, 0, stream>>>(q_t, k_t, v, x, out);
}

// Round 3
// 798.263 us; speedup vs baseline: 1.1863x; 1.0696x over previous
//
#include <hip/hip_runtime.h>
#include <hip/hip_bf16.h>

#define B_   8
#define C_   512
#define N_   4096
#define G_   32
#define CPG  16
#define EPSV 1e-6f

typedef short s16x8 __attribute__((ext_vector_type(8)));
typedef float f32x4 __attribute__((ext_vector_type(4)));

__device__ __forceinline__ unsigned short f2bf(float f) {
    unsigned u = __builtin_bit_cast(unsigned, f);
    u += 0x7fffu + ((u >> 16) & 1u);
    return (unsigned short)(u >> 16);
}

// ---------------------------------------------------------------- kernel 1
__global__ __launch_bounds__(256) void gn_stats_k(const float* __restrict__ x,
                                                  float* __restrict__ stats) {
    int blk = blockIdx.x;  // b*32+g
    const float4* p = (const float4*)(x + (size_t)blk * (CPG * N_));
    float s = 0.f, ss = 0.f;
    for (int i = threadIdx.x; i < (CPG * N_) / 4; i += 256) {
        float4 v = p[i];
        s  += v.x + v.y + v.z + v.w;
        ss += v.x * v.x + v.y * v.y + v.z * v.z + v.w * v.w;
    }
    for (int off = 32; off > 0; off >>= 1) {
        s  += __shfl_down(s, off);
        ss += __shfl_down(ss, off);
    }
    __shared__ float r0[4], r1[4];
    int wid = threadIdx.x >> 6;
    if ((threadIdx.x & 63) == 0) { r0[wid] = s; r1[wid] = ss; }
    __syncthreads();
    if (threadIdx.x == 0) {
        s  = r0[0] + r0[1] + r0[2] + r0[3];
        ss = r1[0] + r1[1] + r1[2] + r1[3];
        const float inv = 1.0f / (CPG * N_);
        float mean = s * inv;
        float var  = ss * inv - mean * mean;
        stats[2 * blk]     = mean;
        stats[2 * blk + 1] = rsqrtf(var + EPSV);
    }
}

// ---------------------------------------------------------------- kernel 2
__global__ __launch_bounds__(256) void cvt_w_k(const float* __restrict__ wq,
                                               const float* __restrict__ wk,
                                               const float* __restrict__ wv,
                                               unsigned short* __restrict__ wbf) {
    int i = blockIdx.x * 256 + threadIdx.x;
    const int percc = C_ * C_ / 4;
    const float* src; int li;
    if (i < percc)            { src = wq; li = i; }
    else if (i < 2 * percc)   { src = wk; li = i - percc; }
    else                      { src = wv; li = i - 2 * percc; }
    float4 v = ((const float4*)src)[li];
    unsigned u0 = (unsigned)f2bf(v.x) | ((unsigned)f2bf(v.y) << 16);
    unsigned u1 = (unsigned)f2bf(v.z) | ((unsigned)f2bf(v.w) << 16);
    uint2 o; o.x = u0; o.y = u1;
    *(uint2*)&wbf[(size_t)i * 4] = o;
}

// ---------------------------------------------------------------- kernel 3
__global__ __launch_bounds__(256) void gn_apply_k(const float* __restrict__ x,
                                                  const float* __restrict__ stats,
                                                  const float* __restrict__ gsc,
                                                  const float* __restrict__ gbi,
                                                  unsigned short* __restrict__ h_t) {
    int nt = blockIdx.x, ct = blockIdx.y, b = blockIdx.z;
    int n0 = nt * 64, c0 = ct * 64;
    __shared__ unsigned short T[64][72];
    int t = threadIdx.x;
    int cl = t >> 2, ch = t & 3;
    int c = c0 + cl;
    int g = c >> 4;
    float mean = stats[(b * G_ + g) * 2];
    float rstd = stats[(b * G_ + g) * 2 + 1];
    float sc = gsc[c] * rstd;
    float bi = gbi[c] - mean * sc;
    const float* xr = x + (size_t)(b * C_ + c) * N_ + n0 + ch * 16;
    #pragma unroll
    for (int q = 0; q < 4; ++q) {
        float4 v = *(const float4*)(xr + q * 4);
        int nl = ch * 16 + q * 4;
        T[nl + 0][cl] = f2bf(fmaf(v.x, sc, bi));
        T[nl + 1][cl] = f2bf(fmaf(v.y, sc, bi));
        T[nl + 2][cl] = f2bf(fmaf(v.z, sc, bi));
        T[nl + 3][cl] = f2bf(fmaf(v.w, sc, bi));
    }
    __syncthreads();
    #pragma unroll
    for (int it = 0; it < 2; ++it) {
        int id = t + it * 256;
        int nl = id >> 3, part = id & 7;
        s16x8 val = *(const s16x8*)&T[nl][part * 8];
        *(s16x8*)&h_t[((size_t)b * N_ + n0 + nl) * C_ + c0 + part * 8] = val;
    }
}

// ---------------------------------------------------------------- kernel 4
__global__ __launch_bounds__(256) void qkv_k(const unsigned short* __restrict__ h_t,
                                             const unsigned short* __restrict__ wbf,
                                             const float* __restrict__ bq,
                                             const float* __restrict__ bk,
                                             const float* __restrict__ bv,
                                             unsigned short* __restrict__ q_t,
                                             unsigned short* __restrict__ k_t,
                                             unsigned short* __restrict__ vv) {
    int which = blockIdx.z % 3;
    int b     = blockIdx.z / 3;
    int bx = blockIdx.x, by = blockIdx.y;
    const unsigned short* A;
    const unsigned short* Bm;
    unsigned short* Cm;
    const float* bias;
    int m0, n0; size_t ldc; bool biasRow;
    const unsigned short* hb = h_t + (size_t)b * N_ * C_;
    if (which < 2) {
        A = hb; Bm = wbf + (size_t)which * C_ * C_;
        Cm = (which == 0 ? q_t : k_t) + (size_t)b * N_ * C_;
        bias = (which == 0 ? bq : bk);
        m0 = bx * 128; n0 = by * 128; ldc = C_; biasRow = false;
    } else {
        A = wbf + (size_t)2 * C_ * C_; Bm = hb;
        Cm = vv + (size_t)b * C_ * N_;
        bias = bv;
        m0 = by * 128; n0 = bx * 128; ldc = N_; biasRow = true;
    }

    __shared__ char smem[34816];
    unsigned short* Al = (unsigned short*)smem;
    unsigned short* Bl = Al + 128 * 40;
    unsigned short* El = (unsigned short*)smem;

    int t = threadIdx.x;
    int wid = t >> 6, lane = t & 63;
    int wm = (wid >> 1) * 64, wn = (wid & 1) * 64;
    int lr = lane & 15, lg = lane >> 4;

    f32x4 acc[4][4] = {};
    for (int k0 = 0; k0 < C_; k0 += 32) {
        __syncthreads();
        #pragma unroll
        for (int it = 0; it < 2; ++it) {
            int id = t + it * 256;
            int row = id >> 2, ch = id & 3;
            *(s16x8*)&Al[row * 40 + ch * 8] =
                *(const s16x8*)&A[(size_t)(m0 + row) * C_ + k0 + ch * 8];
            *(s16x8*)&Bl[row * 40 + ch * 8] =
                *(const s16x8*)&Bm[(size_t)(n0 + row) * C_ + k0 + ch * 8];
        }
        __syncthreads();
        s16x8 a[4], bb[4];
        #pragma unroll
        for (int i = 0; i < 4; ++i) a[i]  = *(const s16x8*)&Al[(wm + i * 16 + lr) * 40 + lg * 8];
        #pragma unroll
        for (int j = 0; j < 4; ++j) bb[j] = *(const s16x8*)&Bl[(wn + j * 16 + lr) * 40 + lg * 8];
        #pragma unroll
        for (int i = 0; i < 4; ++i)
            #pragma unroll
            for (int j = 0; j < 4; ++j)
                acc[i][j] = __builtin_amdgcn_mfma_f32_16x16x32_bf16(a[i], bb[j], acc[i][j], 0, 0, 0);
    }

    float rb[4][4], cb[4];
    #pragma unroll
    for (int i = 0; i < 4; ++i)
        #pragma unroll
        for (int r = 0; r < 4; ++r)
            rb[i][r] = biasRow ? bias[m0 + wm + i * 16 + lg * 4 + r] : 0.f;
    #pragma unroll
    for (int j = 0; j < 4; ++j)
        cb[j] = biasRow ? 0.f : bias[n0 + wn + j * 16 + lr];

    __syncthreads();
    #pragma unroll
    for (int i = 0; i < 4; ++i)
        #pragma unroll
        for (int j = 0; j < 4; ++j) {
            int col = wn + j * 16 + lr;
            #pragma unroll
            for (int r = 0; r < 4; ++r) {
                int row = wm + i * 16 + lg * 4 + r;
                El[row * 136 + col] = f2bf(acc[i][j][r] + rb[i][r] + cb[j]);
            }
        }
    __syncthreads();
    #pragma unroll
    for (int it = 0; it < 8; ++it) {
        int id = t + it * 256;
        int row = id >> 4, part = id & 15;
        *(s16x8*)&Cm[(size_t)(m0 + row) * ldc + n0 + part * 8] =
            *(const s16x8*)&El[row * 136 + part * 8];
    }
}

// ---------------------------------------------------------------- kernel 5
__global__ __launch_bounds__(512) void zeroL_k(float* __restrict__ L) {
    L[blockIdx.x * 512 + threadIdx.x] = 0.f;
}

// ---------------------------------------------------------------- kernel 6
// S-GEMM: for batch pair. Ptil[z][i][j] = exp2(scale*log2e * sum_c q[i][c]k[j][c])
// plus atomic row-sums into L[b][i].
__global__ __launch_bounds__(256) void sgemm_k(const unsigned short* __restrict__ q_t,
                                               const unsigned short* __restrict__ k_t,
                                               unsigned short* __restrict__ Ptil,
                                               float* __restrict__ L,
                                               int bpair) {
    int z = blockIdx.z;
    int b = bpair * 2 + z;
    const unsigned short* A = q_t + (size_t)b * N_ * C_;
    const unsigned short* Bm = k_t + (size_t)b * N_ * C_;
    unsigned short* Cm = Ptil + (size_t)z * N_ * N_;
    int m0 = blockIdx.y * 128, n0 = blockIdx.x * 128;

    __shared__ char smem[34816];
    unsigned short* Al = (unsigned short*)smem;
    unsigned short* Bl = Al + 128 * 40;
    unsigned short* El = (unsigned short*)smem;

    int t = threadIdx.x;
    int wid = t >> 6, lane = t & 63;
    int wm = (wid >> 1) * 64, wn = (wid & 1) * 64;
    int lr = lane & 15, lg = lane >> 4;

    f32x4 acc[4][4] = {};
    for (int k0 = 0; k0 < C_; k0 += 32) {
        __syncthreads();
        #pragma unroll
        for (int it = 0; it < 2; ++it) {
            int id = t + it * 256;
            int row = id >> 2, ch = id & 3;
            *(s16x8*)&Al[row * 40 + ch * 8] =
                *(const s16x8*)&A[(size_t)(m0 + row) * C_ + k0 + ch * 8];
            *(s16x8*)&Bl[row * 40 + ch * 8] =
                *(const s16x8*)&Bm[(size_t)(n0 + row) * C_ + k0 + ch * 8];
        }
        __syncthreads();
        s16x8 a[4], bb[4];
        #pragma unroll
        for (int i = 0; i < 4; ++i) a[i]  = *(const s16x8*)&Al[(wm + i * 16 + lr) * 40 + lg * 8];
        #pragma unroll
        for (int j = 0; j < 4; ++j) bb[j] = *(const s16x8*)&Bl[(wn + j * 16 + lr) * 40 + lg * 8];
        #pragma unroll
        for (int i = 0; i < 4; ++i)
            #pragma unroll
            for (int j = 0; j < 4; ++j)
                acc[i][j] = __builtin_amdgcn_mfma_f32_16x16x32_bf16(a[i], bb[j], acc[i][j], 0, 0, 0);
    }

    const float SCL2 = 0.06375862f;  // log2(e) / sqrt(512)
    float rsum[4][4];
    #pragma unroll
    for (int i = 0; i < 4; ++i)
        #pragma unroll
        for (int r = 0; r < 4; ++r) rsum[i][r] = 0.f;

    __syncthreads();
    #pragma unroll
    for (int i = 0; i < 4; ++i)
        #pragma unroll
        for (int j = 0; j < 4; ++j) {
            int col = wn + j * 16 + lr;
            #pragma unroll
            for (int r = 0; r < 4; ++r) {
                float p = exp2f(acc[i][j][r] * SCL2);
                rsum[i][r] += p;
                El[(wm + i * 16 + lg * 4 + r) * 136 + col] = f2bf(p);
            }
        }
    // row-sum reduce across the 16 lr lanes (same row), then atomic
    #pragma unroll
    for (int msk = 8; msk >= 1; msk >>= 1)
        #pragma unroll
        for (int i = 0; i < 4; ++i)
            #pragma unroll
            for (int r = 0; r < 4; ++r)
                rsum[i][r] += __shfl_xor(rsum[i][r], msk);
    if (lr == 0) {
        #pragma unroll
        for (int i = 0; i < 4; ++i)
            #pragma unroll
            for (int r = 0; r < 4; ++r)
                atomicAdd(&L[(size_t)b * N_ + m0 + wm + i * 16 + lg * 4 + r], rsum[i][r]);
    }
    __syncthreads();
    #pragma unroll
    for (int it = 0; it < 8; ++it) {
        int id = t + it * 256;
        int row = id >> 4, part = id & 15;
        *(s16x8*)&Cm[(size_t)(m0 + row) * N_ + n0 + part * 8] =
            *(const s16x8*)&El[row * 136 + part * 8];
    }
}

// ---------------------------------------------------------------- kernel 7
// PV-GEMM: out[b][c][i] = x[b][c][i] + (sum_j v[c][j] * Ptil[i][j]) / L[b][i]
__global__ __launch_bounds__(256) void pv_k(const unsigned short* __restrict__ vv,
                                            const unsigned short* __restrict__ Ptil,
                                            const float* __restrict__ L,
                                            const float* __restrict__ x,
                                            float* __restrict__ out,
                                            int bpair) {
    int z = blockIdx.z;
    int b = bpair * 2 + z;
    const unsigned short* A = vv + (size_t)b * C_ * N_;      // [c][j]
    const unsigned short* Bm = Ptil + (size_t)z * N_ * N_;   // [i][j]
    int m0 = blockIdx.y * 128, n0 = blockIdx.x * 128;
    const float* xb = x + (size_t)b * C_ * N_;
    float* ob = out + (size_t)b * C_ * N_;

    __shared__ char smem[34816];
    unsigned short* Al = (unsigned short*)smem;
    unsigned short* Bl = Al + 128 * 40;

    int t = threadIdx.x;
    int wid = t >> 6, lane = t & 63;
    int wm = (wid >> 1) * 64, wn = (wid & 1) * 64;
    int lr = lane & 15, lg = lane >> 4;

    f32x4 acc[4][4] = {};
    for (int k0 = 0; k0 < N_; k0 += 32) {
        __syncthreads();
        #pragma unroll
        for (int it = 0; it < 2; ++it) {
            int id = t + it * 256;
            int row = id >> 2, ch = id & 3;
            *(s16x8*)&Al[row * 40 + ch * 8] =
                *(const s16x8*)&A[(size_t)(m0 + row) * N_ + k0 + ch * 8];
            *(s16x8*)&Bl[row * 40 + ch * 8] =
                *(const s16x8*)&Bm[(size_t)(n0 + row) * N_ + k0 + ch * 8];
        }
        __syncthreads();
        s16x8 a[4], bb[4];
        #pragma unroll
        for (int i = 0; i < 4; ++i) a[i]  = *(const s16x8*)&Al[(wm + i * 16 + lr) * 40 + lg * 8];
        #pragma unroll
        for (int j = 0; j < 4; ++j) bb[j] = *(const s16x8*)&Bl[(wn + j * 16 + lr) * 40 + lg * 8];
        #pragma unroll
        for (int i = 0; i < 4; ++i)
            #pragma unroll
            for (int j = 0; j < 4; ++j)
                acc[i][j] = __builtin_amdgcn_mfma_f32_16x16x32_bf16(a[i], bb[j], acc[i][j], 0, 0, 0);
    }

    // epilogue: divide by L (per output column = spatial index), add x, store f32
    #pragma unroll
    for (int j = 0; j < 4; ++j) {
        int col = n0 + wn + j * 16 + lr;
        float rl = 1.0f / L[(size_t)b * N_ + col];
        #pragma unroll
        for (int i = 0; i < 4; ++i) {
            #pragma unroll
            for (int r = 0; r < 4; ++r) {
                int row = m0 + wm + i * 16 + lg * 4 + r;
                size_t off = (size_t)row * N_ + col;
                ob[off] = xb[off] + acc[i][j][r] * rl;
            }
        }
    }
}

// ---------------------------------------------------------------- launch
extern "C" void kernel_launch(void* const* d_in, const int* in_sizes, int n_in,
                              void* d_out, int out_size, void* d_ws, size_t ws_size,
                              hipStream_t stream) {
    const float* x   = (const float*)d_in[0];
    const float* gsc = (const float*)d_in[1];
    const float* gbi = (const float*)d_in[2];
    const float* wq  = (const float*)d_in[3];
    const float* bq  = (const float*)d_in[4];
    const float* wk  = (const float*)d_in[5];
    const float* bk  = (const float*)d_in[6];
    const float* wv  = (const float*)d_in[7];
    const float* bv  = (const float*)d_in[8];
    float* out = (float*)d_out;

    const size_t elems = (size_t)B_ * N_ * C_;   // 16.7M
    unsigned short* q_t   = (unsigned short*)d_ws;
    unsigned short* k_t   = q_t + elems;
    unsigned short* v     = k_t + elems;
    float*          stats = (float*)(v + elems);
    unsigned short* wbf   = (unsigned short*)(stats + 2 * B_ * G_);
    float*          L     = (float*)(wbf + (size_t)3 * C_ * C_);
    unsigned short* Ptil  = (unsigned short*)(L + (size_t)B_ * N_);   // 2 x 32MB
    unsigned short* h_t   = (unsigned short*)d_out;  // dead before pv writes

    gn_stats_k<<<B_ * G_, 256, 0, stream>>>(x, stats);
    cvt_w_k<<<(3 * C_ * C_ / 4) / 256, 256, 0, stream>>>(wq, wk, wv, wbf);
    gn_apply_k<<<dim3(N_ / 64, C_ / 64, B_), 256, 0, stream>>>(x, stats, gsc, gbi, h_t);
    qkv_k<<<dim3(32, 4, 3 * B_), 256, 0, stream>>>(h_t, wbf, bq, bk, bv, q_t, k_t, v);
    zeroL_k<<<(B_ * N_) / 512, 512, 0, stream>>>(L);
    for (int p = 0; p < 4; ++p) {
        sgemm_k<<<dim3(32, 32, 2), 256, 0, stream>>>(q_t, k_t, Ptil, L, p);
        pv_k<<<dim3(32, 4, 2), 256, 0, stream>>>(v, Ptil, L, x, out, p);
    }
}

// Round 4
// 714.178 us; speedup vs baseline: 1.3260x; 1.1177x over previous
//
#include <hip/hip_runtime.h>
#include <hip/hip_bf16.h>

#define B_   8
#define C_   512
#define N_   4096
#define G_   32
#define CPG  16
#define EPSV 1e-6f

typedef short s16x8 __attribute__((ext_vector_type(8)));
typedef float f32x4 __attribute__((ext_vector_type(4)));

__device__ __forceinline__ unsigned short f2bf(float f) {
    unsigned u = __builtin_bit_cast(unsigned, f);
    u += 0x7fffu + ((u >> 16) & 1u);
    return (unsigned short)(u >> 16);
}

__device__ __forceinline__ void gload_lds16(const unsigned short* g, unsigned short* l) {
    __builtin_amdgcn_global_load_lds((const __attribute__((address_space(1))) void*)g,
                                     (__attribute__((address_space(3))) void*)l, 16, 0, 0);
}

// ---------------------------------------------------------------- kernel 1
__global__ __launch_bounds__(256) void gn_stats_k(const float* __restrict__ x,
                                                  float* __restrict__ stats) {
    int blk = blockIdx.x;  // b*32+g
    const float4* p = (const float4*)(x + (size_t)blk * (CPG * N_));
    float s = 0.f, ss = 0.f;
    for (int i = threadIdx.x; i < (CPG * N_) / 4; i += 256) {
        float4 v = p[i];
        s  += v.x + v.y + v.z + v.w;
        ss += v.x * v.x + v.y * v.y + v.z * v.z + v.w * v.w;
    }
    for (int off = 32; off > 0; off >>= 1) {
        s  += __shfl_down(s, off);
        ss += __shfl_down(ss, off);
    }
    __shared__ float r0[4], r1[4];
    int wid = threadIdx.x >> 6;
    if ((threadIdx.x & 63) == 0) { r0[wid] = s; r1[wid] = ss; }
    __syncthreads();
    if (threadIdx.x == 0) {
        s  = r0[0] + r0[1] + r0[2] + r0[3];
        ss = r1[0] + r1[1] + r1[2] + r1[3];
        const float inv = 1.0f / (CPG * N_);
        float mean = s * inv;
        float var  = ss * inv - mean * mean;
        stats[2 * blk]     = mean;
        stats[2 * blk + 1] = rsqrtf(var + EPSV);
    }
}

// ---------------------------------------------------------------- kernel 2
__global__ __launch_bounds__(256) void cvt_w_k(const float* __restrict__ wq,
                                               const float* __restrict__ wk,
                                               const float* __restrict__ wv,
                                               unsigned short* __restrict__ wbf) {
    int i = blockIdx.x * 256 + threadIdx.x;
    const int percc = C_ * C_ / 4;
    const float* src; int li;
    if (i < percc)            { src = wq; li = i; }
    else if (i < 2 * percc)   { src = wk; li = i - percc; }
    else                      { src = wv; li = i - 2 * percc; }
    float4 v = ((const float4*)src)[li];
    unsigned u0 = (unsigned)f2bf(v.x) | ((unsigned)f2bf(v.y) << 16);
    unsigned u1 = (unsigned)f2bf(v.z) | ((unsigned)f2bf(v.w) << 16);
    uint2 o; o.x = u0; o.y = u1;
    *(uint2*)&wbf[(size_t)i * 4] = o;
}

// ---------------------------------------------------------------- kernel 3
__global__ __launch_bounds__(256) void gn_apply_k(const float* __restrict__ x,
                                                  const float* __restrict__ stats,
                                                  const float* __restrict__ gsc,
                                                  const float* __restrict__ gbi,
                                                  unsigned short* __restrict__ h_t) {
    int nt = blockIdx.x, ct = blockIdx.y, b = blockIdx.z;
    int n0 = nt * 64, c0 = ct * 64;
    __shared__ unsigned short T[64][72];
    int t = threadIdx.x;
    int cl = t >> 2, ch = t & 3;
    int c = c0 + cl;
    int g = c >> 4;
    float mean = stats[(b * G_ + g) * 2];
    float rstd = stats[(b * G_ + g) * 2 + 1];
    float sc = gsc[c] * rstd;
    float bi = gbi[c] - mean * sc;
    const float* xr = x + (size_t)(b * C_ + c) * N_ + n0 + ch * 16;
    #pragma unroll
    for (int q = 0; q < 4; ++q) {
        float4 v = *(const float4*)(xr + q * 4);
        int nl = ch * 16 + q * 4;
        T[nl + 0][cl] = f2bf(fmaf(v.x, sc, bi));
        T[nl + 1][cl] = f2bf(fmaf(v.y, sc, bi));
        T[nl + 2][cl] = f2bf(fmaf(v.z, sc, bi));
        T[nl + 3][cl] = f2bf(fmaf(v.w, sc, bi));
    }
    __syncthreads();
    #pragma unroll
    for (int it = 0; it < 2; ++it) {
        int id = t + it * 256;
        int nl = id >> 3, part = id & 7;
        s16x8 val = *(const s16x8*)&T[nl][part * 8];
        *(s16x8*)&h_t[((size_t)b * N_ + n0 + nl) * C_ + c0 + part * 8] = val;
    }
}

// ---------------------------------------------------------------- 2-phase GEMM core
// C128x128 = A[128 rows of ldA] . B[128 rows of ldB]^T, K = ksteps*32, both K-contig.
// Double-buffered LDS staged via global_load_lds (issued before compute of current
// step -> loads in flight during MFMA; single barrier per K-step).
// Al/Bl: 2 x 4096 shorts each (16KB each).
__device__ __forceinline__ void gemm_core(const unsigned short* A, int ldA,
                                          const unsigned short* Bm, int ldB,
                                          unsigned short* Al, unsigned short* Bl,
                                          f32x4 (&acc)[4][4], int ksteps, int t) {
    int w = t >> 6, l = t & 63;
    int wm = (w >> 1) * 64, wn = (w & 1) * 64;
    int lr = l & 15, lg = l >> 4;
    int srow = w * 16 + (l >> 2);      // staging row within 64-row half
    int sp   = (l & 3) * 8;            // staging col (shorts)

    // prologue: stage step 0 into buf 0
    #pragma unroll
    for (int it = 0; it < 2; ++it) {
        gload_lds16(&A [(size_t)(it * 64 + srow) * ldA + sp], &Al[it * 2048 + w * 512 + l * 8]);
        gload_lds16(&Bm[(size_t)(it * 64 + srow) * ldB + sp], &Bl[it * 2048 + w * 512 + l * 8]);
    }
    __syncthreads();

    int cur = 0;
    for (int s = 0; s < ksteps; ++s) {
        if (s + 1 < ksteps) {
            const unsigned short* ga = A  + (s + 1) * 32;
            const unsigned short* gb = Bm + (s + 1) * 32;
            int off = (cur ^ 1) * 4096;
            #pragma unroll
            for (int it = 0; it < 2; ++it) {
                gload_lds16(&ga[(size_t)(it * 64 + srow) * ldA + sp], &Al[off + it * 2048 + w * 512 + l * 8]);
                gload_lds16(&gb[(size_t)(it * 64 + srow) * ldB + sp], &Bl[off + it * 2048 + w * 512 + l * 8]);
            }
        }
        const unsigned short* la = Al + cur * 4096;
        const unsigned short* lb = Bl + cur * 4096;
        s16x8 a[4], b[4];
        #pragma unroll
        for (int i = 0; i < 4; ++i) a[i] = *(const s16x8*)&la[(wm + i * 16 + lr) * 32 + lg * 8];
        #pragma unroll
        for (int j = 0; j < 4; ++j) b[j] = *(const s16x8*)&lb[(wn + j * 16 + lr) * 32 + lg * 8];
        #pragma unroll
        for (int i = 0; i < 4; ++i)
            #pragma unroll
            for (int j = 0; j < 4; ++j)
                acc[i][j] = __builtin_amdgcn_mfma_f32_16x16x32_bf16(a[i], b[j], acc[i][j], 0, 0, 0);
        __syncthreads();   // drains prefetch (vmcnt0) + guards LDS reuse
        cur ^= 1;
    }
}

// ---------------------------------------------------------------- kernel 4: QKV projections
__global__ __launch_bounds__(256, 4) void qkv_k(const unsigned short* __restrict__ h_t,
                                                const unsigned short* __restrict__ wbf,
                                                const float* __restrict__ bq,
                                                const float* __restrict__ bk,
                                                const float* __restrict__ bv,
                                                unsigned short* __restrict__ q_t,
                                                unsigned short* __restrict__ k_t,
                                                unsigned short* __restrict__ vv) {
    int which = blockIdx.z % 3;
    int b     = blockIdx.z / 3;
    int bx = blockIdx.x, by = blockIdx.y;
    const unsigned short* A;
    const unsigned short* Bm;
    unsigned short* Cm;
    const float* bias;
    int m0, n0; size_t ldc; bool biasRow;
    const unsigned short* hb = h_t + (size_t)b * N_ * C_;
    if (which < 2) {
        A = hb; Bm = wbf + (size_t)which * C_ * C_;
        Cm = (which == 0 ? q_t : k_t) + (size_t)b * N_ * C_;
        bias = (which == 0 ? bq : bk);
        m0 = bx * 128; n0 = by * 128; ldc = C_; biasRow = false;
    } else {
        A = wbf + (size_t)2 * C_ * C_; Bm = hb;
        Cm = vv + (size_t)b * C_ * N_;
        bias = bv;
        m0 = by * 128; n0 = bx * 128; ldc = N_; biasRow = true;
    }

    __shared__ char smem[35072];
    unsigned short* Al = (unsigned short*)smem;          // 2 x 4096
    unsigned short* Bl = Al + 8192;                      // 2 x 4096
    unsigned short* El = (unsigned short*)smem;          // epilogue alias [128][136]

    int t = threadIdx.x;
    int wid = t >> 6, lane = t & 63;
    int wm = (wid >> 1) * 64, wn = (wid & 1) * 64;
    int lr = lane & 15, lg = lane >> 4;

    f32x4 acc[4][4] = {};
    gemm_core(A + (size_t)m0 * C_, C_, Bm + (size_t)n0 * C_, C_, Al, Bl, acc, C_ / 32, t);

    float rb[4][4], cb[4];
    #pragma unroll
    for (int i = 0; i < 4; ++i)
        #pragma unroll
        for (int r = 0; r < 4; ++r)
            rb[i][r] = biasRow ? bias[m0 + wm + i * 16 + lg * 4 + r] : 0.f;
    #pragma unroll
    for (int j = 0; j < 4; ++j)
        cb[j] = biasRow ? 0.f : bias[n0 + wn + j * 16 + lr];

    #pragma unroll
    for (int i = 0; i < 4; ++i)
        #pragma unroll
        for (int j = 0; j < 4; ++j) {
            int col = wn + j * 16 + lr;
            #pragma unroll
            for (int r = 0; r < 4; ++r) {
                int row = wm + i * 16 + lg * 4 + r;
                El[row * 136 + col] = f2bf(acc[i][j][r] + rb[i][r] + cb[j]);
            }
        }
    __syncthreads();
    #pragma unroll
    for (int it = 0; it < 8; ++it) {
        int id = t + it * 256;
        int row = id >> 4, part = id & 15;
        *(s16x8*)&Cm[(size_t)(m0 + row) * ldc + n0 + part * 8] =
            *(const s16x8*)&El[row * 136 + part * 8];
    }
}

// ---------------------------------------------------------------- kernel 5
__global__ __launch_bounds__(512) void zeroL_k(float* __restrict__ L) {
    L[blockIdx.x * 512 + threadIdx.x] = 0.f;
}

// ---------------------------------------------------------------- kernel 6
// Ptil[slot][i][j] = exp2(SCL2 * sum_c q[i][c]k[j][c]); atomic row-sums into L[b][i].
// slot = blockIdx.z, b = bbase + blockIdx.z.
__global__ __launch_bounds__(256, 4) void sgemm_k(const unsigned short* __restrict__ q_t,
                                                  const unsigned short* __restrict__ k_t,
                                                  unsigned short* __restrict__ Ptil,
                                                  float* __restrict__ L,
                                                  int bbase) {
    int z = blockIdx.z;
    int b = bbase + z;
    const unsigned short* A  = q_t + (size_t)b * N_ * C_;
    const unsigned short* Bm = k_t + (size_t)b * N_ * C_;
    unsigned short* Cm = Ptil + (size_t)z * N_ * N_;
    int m0 = blockIdx.y * 128, n0 = blockIdx.x * 128;

    __shared__ char smem[35072];
    unsigned short* Al = (unsigned short*)smem;
    unsigned short* Bl = Al + 8192;
    unsigned short* El = (unsigned short*)smem;

    int t = threadIdx.x;
    int wid = t >> 6, lane = t & 63;
    int wm = (wid >> 1) * 64, wn = (wid & 1) * 64;
    int lr = lane & 15, lg = lane >> 4;

    f32x4 acc[4][4] = {};
    gemm_core(A + (size_t)m0 * C_, C_, Bm + (size_t)n0 * C_, C_, Al, Bl, acc, C_ / 32, t);

    const float SCL2 = 0.06375862f;  // log2(e) / sqrt(512)
    float rsum[4][4];
    #pragma unroll
    for (int i = 0; i < 4; ++i)
        #pragma unroll
        for (int r = 0; r < 4; ++r) rsum[i][r] = 0.f;

    #pragma unroll
    for (int i = 0; i < 4; ++i)
        #pragma unroll
        for (int j = 0; j < 4; ++j) {
            int col = wn + j * 16 + lr;
            #pragma unroll
            for (int r = 0; r < 4; ++r) {
                float p = exp2f(acc[i][j][r] * SCL2);
                rsum[i][r] += p;
                El[(wm + i * 16 + lg * 4 + r) * 136 + col] = f2bf(p);
            }
        }
    #pragma unroll
    for (int msk = 8; msk >= 1; msk >>= 1)
        #pragma unroll
        for (int i = 0; i < 4; ++i)
            #pragma unroll
            for (int r = 0; r < 4; ++r)
                rsum[i][r] += __shfl_xor(rsum[i][r], msk);
    if (lr == 0) {
        #pragma unroll
        for (int i = 0; i < 4; ++i)
            #pragma unroll
            for (int r = 0; r < 4; ++r)
                atomicAdd(&L[(size_t)b * N_ + m0 + wm + i * 16 + lg * 4 + r], rsum[i][r]);
    }
    __syncthreads();
    #pragma unroll
    for (int it = 0; it < 8; ++it) {
        int id = t + it * 256;
        int row = id >> 4, part = id & 15;
        *(s16x8*)&Cm[(size_t)(m0 + row) * N_ + n0 + part * 8] =
            *(const s16x8*)&El[row * 136 + part * 8];
    }
}

// ---------------------------------------------------------------- kernel 7
// out[b][c][i] = x[b][c][i] + (sum_j v[c][j] * Ptil[slot][i][j]) / L[b][i]
__global__ __launch_bounds__(256, 4) void pv_k(const unsigned short* __restrict__ vv,
                                               const unsigned short* __restrict__ Ptil,
                                               const float* __restrict__ L,
                                               const float* __restrict__ x,
                                               float* __restrict__ out,
                                               int bbase) {
    int z = blockIdx.z;
    int b = bbase + z;
    const unsigned short* A  = vv + (size_t)b * C_ * N_;      // [c][j]
    const unsigned short* Bm = Ptil + (size_t)z * N_ * N_;    // [i][j]
    int m0 = blockIdx.y * 128, n0 = blockIdx.x * 128;
    const float* xb = x + (size_t)b * C_ * N_;
    float* ob = out + (size_t)b * C_ * N_;

    __shared__ char smem[32768];
    unsigned short* Al = (unsigned short*)smem;
    unsigned short* Bl = Al + 8192;

    int t = threadIdx.x;
    int wid = t >> 6, lane = t & 63;
    int wm = (wid >> 1) * 64, wn = (wid & 1) * 64;
    int lr = lane & 15, lg = lane >> 4;

    f32x4 acc[4][4] = {};
    gemm_core(A + (size_t)m0 * N_, N_, Bm + (size_t)n0 * N_, N_, Al, Bl, acc, N_ / 32, t);

    #pragma unroll
    for (int j = 0; j < 4; ++j) {
        int col = n0 + wn + j * 16 + lr;
        float rl = 1.0f / L[(size_t)b * N_ + col];
        #pragma unroll
        for (int i = 0; i < 4; ++i) {
            #pragma unroll
            for (int r = 0; r < 4; ++r) {
                int row = m0 + wm + i * 16 + lg * 4 + r;
                size_t off = (size_t)row * N_ + col;
                ob[off] = xb[off] + acc[i][j][r] * rl;
            }
        }
    }
}

// ---------------------------------------------------------------- launch
extern "C" void kernel_launch(void* const* d_in, const int* in_sizes, int n_in,
                              void* d_out, int out_size, void* d_ws, size_t ws_size,
                              hipStream_t stream) {
    const float* x   = (const float*)d_in[0];
    const float* gsc = (const float*)d_in[1];
    const float* gbi = (const float*)d_in[2];
    const float* wq  = (const float*)d_in[3];
    const float* bq  = (const float*)d_in[4];
    const float* wk  = (const float*)d_in[5];
    const float* bk  = (const float*)d_in[6];
    const float* wv  = (const float*)d_in[7];
    const float* bv  = (const float*)d_in[8];
    float* out = (float*)d_out;

    const size_t elems = (size_t)B_ * N_ * C_;   // 16.7M
    unsigned short* q_t   = (unsigned short*)d_ws;
    unsigned short* k_t   = q_t + elems;
    unsigned short* v     = k_t + elems;
    float*          stats = (float*)(v + elems);
    unsigned short* wbf   = (unsigned short*)(stats + 2 * B_ * G_);
    float*          L     = (float*)(wbf + (size_t)3 * C_ * C_);
    unsigned short* Ptil  = (unsigned short*)(L + (size_t)B_ * N_);
    unsigned short* h_t   = (unsigned short*)d_out;  // dead before pv writes

    const size_t base_bytes = (size_t)((char*)Ptil - (char*)d_ws);
    const size_t slot_bytes = (size_t)N_ * N_ * 2;
    const bool all8 = ws_size >= base_bytes + 8 * slot_bytes;

    gn_stats_k<<<B_ * G_, 256, 0, stream>>>(x, stats);
    cvt_w_k<<<(3 * C_ * C_ / 4) / 256, 256, 0, stream>>>(wq, wk, wv, wbf);
    gn_apply_k<<<dim3(N_ / 64, C_ / 64, B_), 256, 0, stream>>>(x, stats, gsc, gbi, h_t);
    qkv_k<<<dim3(32, 4, 3 * B_), 256, 0, stream>>>(h_t, wbf, bq, bk, bv, q_t, k_t, v);
    zeroL_k<<<(B_ * N_) / 512, 512, 0, stream>>>(L);
    if (all8) {
        sgemm_k<<<dim3(32, 32, 8), 256, 0, stream>>>(q_t, k_t, Ptil, L, 0);
        pv_k<<<dim3(32, 4, 8), 256, 0, stream>>>(v, Ptil, L, x, out, 0);
    } else {
        for (int p = 0; p < 4; ++p) {
            sgemm_k<<<dim3(32, 32, 2), 256, 0, stream>>>(q_t, k_t, Ptil, L, 2 * p);
            pv_k<<<dim3(32, 4, 2), 256, 0, stream>>>(v, Ptil, L, x, out, 2 * p);
        }
    }
}

// Round 5
// 624.442 us; speedup vs baseline: 1.5166x; 1.1437x over previous
//
#include <hip/hip_runtime.h>
#include <hip/hip_bf16.h>

#define B_   8
#define C_   512
#define N_   4096
#define G_   32
#define CPG  16
#define EPSV 1e-6f

typedef short s16x8 __attribute__((ext_vector_type(8)));
typedef float f32x4 __attribute__((ext_vector_type(4)));

__device__ __forceinline__ unsigned short f2bf(float f) {
    unsigned u = __builtin_bit_cast(unsigned, f);
    u += 0x7fffu + ((u >> 16) & 1u);
    return (unsigned short)(u >> 16);
}

__device__ __forceinline__ void gload_lds16(const unsigned short* g, unsigned short* l) {
    __builtin_amdgcn_global_load_lds((const __attribute__((address_space(1))) void*)g,
                                     (__attribute__((address_space(3))) void*)l, 16, 0, 0);
}

// ---------------------------------------------------------------- kernel 1
__global__ __launch_bounds__(256) void gn_stats_k(const float* __restrict__ x,
                                                  float* __restrict__ stats) {
    int blk = blockIdx.x;  // b*32+g
    const float4* p = (const float4*)(x + (size_t)blk * (CPG * N_));
    float s = 0.f, ss = 0.f;
    for (int i = threadIdx.x; i < (CPG * N_) / 4; i += 256) {
        float4 v = p[i];
        s  += v.x + v.y + v.z + v.w;
        ss += v.x * v.x + v.y * v.y + v.z * v.z + v.w * v.w;
    }
    for (int off = 32; off > 0; off >>= 1) {
        s  += __shfl_down(s, off);
        ss += __shfl_down(ss, off);
    }
    __shared__ float r0[4], r1[4];
    int wid = threadIdx.x >> 6;
    if ((threadIdx.x & 63) == 0) { r0[wid] = s; r1[wid] = ss; }
    __syncthreads();
    if (threadIdx.x == 0) {
        s  = r0[0] + r0[1] + r0[2] + r0[3];
        ss = r1[0] + r1[1] + r1[2] + r1[3];
        const float inv = 1.0f / (CPG * N_);
        float mean = s * inv;
        float var  = ss * inv - mean * mean;
        stats[2 * blk]     = mean;
        stats[2 * blk + 1] = rsqrtf(var + EPSV);
    }
}

// ---------------------------------------------------------------- kernel 2
__global__ __launch_bounds__(256) void cvt_w_k(const float* __restrict__ wq,
                                               const float* __restrict__ wk,
                                               const float* __restrict__ wv,
                                               unsigned short* __restrict__ wbf) {
    int i = blockIdx.x * 256 + threadIdx.x;
    const int percc = C_ * C_ / 4;
    const float* src; int li;
    if (i < percc)            { src = wq; li = i; }
    else if (i < 2 * percc)   { src = wk; li = i - percc; }
    else                      { src = wv; li = i - 2 * percc; }
    float4 v = ((const float4*)src)[li];
    unsigned u0 = (unsigned)f2bf(v.x) | ((unsigned)f2bf(v.y) << 16);
    unsigned u1 = (unsigned)f2bf(v.z) | ((unsigned)f2bf(v.w) << 16);
    uint2 o; o.x = u0; o.y = u1;
    *(uint2*)&wbf[(size_t)i * 4] = o;
}

// ---------------------------------------------------------------- kernel 3
__global__ __launch_bounds__(256) void gn_apply_k(const float* __restrict__ x,
                                                  const float* __restrict__ stats,
                                                  const float* __restrict__ gsc,
                                                  const float* __restrict__ gbi,
                                                  unsigned short* __restrict__ h_t) {
    int nt = blockIdx.x, ct = blockIdx.y, b = blockIdx.z;
    int n0 = nt * 64, c0 = ct * 64;
    __shared__ unsigned short T[64][72];
    int t = threadIdx.x;
    int cl = t >> 2, ch = t & 3;
    int c = c0 + cl;
    int g = c >> 4;
    float mean = stats[(b * G_ + g) * 2];
    float rstd = stats[(b * G_ + g) * 2 + 1];
    float sc = gsc[c] * rstd;
    float bi = gbi[c] - mean * sc;
    const float* xr = x + (size_t)(b * C_ + c) * N_ + n0 + ch * 16;
    #pragma unroll
    for (int q = 0; q < 4; ++q) {
        float4 v = *(const float4*)(xr + q * 4);
        int nl = ch * 16 + q * 4;
        T[nl + 0][cl] = f2bf(fmaf(v.x, sc, bi));
        T[nl + 1][cl] = f2bf(fmaf(v.y, sc, bi));
        T[nl + 2][cl] = f2bf(fmaf(v.z, sc, bi));
        T[nl + 3][cl] = f2bf(fmaf(v.w, sc, bi));
    }
    __syncthreads();
    #pragma unroll
    for (int it = 0; it < 2; ++it) {
        int id = t + it * 256;
        int nl = id >> 3, part = id & 7;
        s16x8 val = *(const s16x8*)&T[nl][part * 8];
        *(s16x8*)&h_t[((size_t)b * N_ + n0 + nl) * C_ + c0 + part * 8] = val;
    }
}

// ---------------------------------------------------------------- kernel 3b: out = x (for atomic pv)
__global__ __launch_bounds__(256) void copyx_k(const float* __restrict__ x,
                                               float* __restrict__ out) {
    const size_t total4 = (size_t)B_ * C_ * N_ / 4;
    size_t stride = (size_t)gridDim.x * 256;
    for (size_t i = blockIdx.x * 256 + threadIdx.x; i < total4; i += stride)
        ((float4*)out)[i] = ((const float4*)x)[i];
}

// ---------------------------------------------------------------- 2-phase GEMM core
// C128x128 = A[128 rows of ldA] . B[128 rows of ldB]^T, K = ksteps*32, both K-contig.
// global_load_lds prefetch of step s+1 issued before compute of step s.
__device__ __forceinline__ void gemm_core(const unsigned short* A, int ldA,
                                          const unsigned short* Bm, int ldB,
                                          unsigned short* Al, unsigned short* Bl,
                                          f32x4 (&acc)[4][4], int ksteps, int t) {
    int w = t >> 6, l = t & 63;
    int wm = (w >> 1) * 64, wn = (w & 1) * 64;
    int lr = l & 15, lg = l >> 4;
    int srow = w * 16 + (l >> 2);
    int sp   = (l & 3) * 8;

    #pragma unroll
    for (int it = 0; it < 2; ++it) {
        gload_lds16(&A [(size_t)(it * 64 + srow) * ldA + sp], &Al[it * 2048 + w * 512 + l * 8]);
        gload_lds16(&Bm[(size_t)(it * 64 + srow) * ldB + sp], &Bl[it * 2048 + w * 512 + l * 8]);
    }
    __syncthreads();

    int cur = 0;
    for (int s = 0; s < ksteps; ++s) {
        if (s + 1 < ksteps) {
            const unsigned short* ga = A  + (s + 1) * 32;
            const unsigned short* gb = Bm + (s + 1) * 32;
            int off = (cur ^ 1) * 4096;
            #pragma unroll
            for (int it = 0; it < 2; ++it) {
                gload_lds16(&ga[(size_t)(it * 64 + srow) * ldA + sp], &Al[off + it * 2048 + w * 512 + l * 8]);
                gload_lds16(&gb[(size_t)(it * 64 + srow) * ldB + sp], &Bl[off + it * 2048 + w * 512 + l * 8]);
            }
        }
        const unsigned short* la = Al + cur * 4096;
        const unsigned short* lb = Bl + cur * 4096;
        s16x8 a[4], b[4];
        #pragma unroll
        for (int i = 0; i < 4; ++i) a[i] = *(const s16x8*)&la[(wm + i * 16 + lr) * 32 + lg * 8];
        #pragma unroll
        for (int j = 0; j < 4; ++j) b[j] = *(const s16x8*)&lb[(wn + j * 16 + lr) * 32 + lg * 8];
        #pragma unroll
        for (int i = 0; i < 4; ++i)
            #pragma unroll
            for (int j = 0; j < 4; ++j)
                acc[i][j] = __builtin_amdgcn_mfma_f32_16x16x32_bf16(a[i], b[j], acc[i][j], 0, 0, 0);
        __syncthreads();
        cur ^= 1;
    }
}

// ---------------------------------------------------------------- kernel 4: QKV projections
__global__ __launch_bounds__(256, 4) void qkv_k(const unsigned short* __restrict__ h_t,
                                                const unsigned short* __restrict__ wbf,
                                                const float* __restrict__ bq,
                                                const float* __restrict__ bk,
                                                const float* __restrict__ bv,
                                                unsigned short* __restrict__ q_t,
                                                unsigned short* __restrict__ k_t,
                                                unsigned short* __restrict__ vv) {
    int which = blockIdx.z % 3;
    int b     = blockIdx.z / 3;
    int bx = blockIdx.x, by = blockIdx.y;
    const unsigned short* A;
    const unsigned short* Bm;
    unsigned short* Cm;
    const float* bias;
    int m0, n0; size_t ldc; bool biasRow;
    const unsigned short* hb = h_t + (size_t)b * N_ * C_;
    if (which < 2) {
        A = hb; Bm = wbf + (size_t)which * C_ * C_;
        Cm = (which == 0 ? q_t : k_t) + (size_t)b * N_ * C_;
        bias = (which == 0 ? bq : bk);
        m0 = bx * 128; n0 = by * 128; ldc = C_; biasRow = false;
    } else {
        A = wbf + (size_t)2 * C_ * C_; Bm = hb;
        Cm = vv + (size_t)b * C_ * N_;
        bias = bv;
        m0 = by * 128; n0 = bx * 128; ldc = N_; biasRow = true;
    }

    __shared__ char smem[35072];
    unsigned short* Al = (unsigned short*)smem;
    unsigned short* Bl = Al + 8192;
    unsigned short* El = (unsigned short*)smem;

    int t = threadIdx.x;
    int wid = t >> 6, lane = t & 63;
    int wm = (wid >> 1) * 64, wn = (wid & 1) * 64;
    int lr = lane & 15, lg = lane >> 4;

    f32x4 acc[4][4] = {};
    gemm_core(A + (size_t)m0 * C_, C_, Bm + (size_t)n0 * C_, C_, Al, Bl, acc, C_ / 32, t);

    float rb[4][4], cb[4];
    #pragma unroll
    for (int i = 0; i < 4; ++i)
        #pragma unroll
        for (int r = 0; r < 4; ++r)
            rb[i][r] = biasRow ? bias[m0 + wm + i * 16 + lg * 4 + r] : 0.f;
    #pragma unroll
    for (int j = 0; j < 4; ++j)
        cb[j] = biasRow ? 0.f : bias[n0 + wn + j * 16 + lr];

    #pragma unroll
    for (int i = 0; i < 4; ++i)
        #pragma unroll
        for (int j = 0; j < 4; ++j) {
            int col = wn + j * 16 + lr;
            #pragma unroll
            for (int r = 0; r < 4; ++r) {
                int row = wm + i * 16 + lg * 4 + r;
                El[row * 136 + col] = f2bf(acc[i][j][r] + rb[i][r] + cb[j]);
            }
        }
    __syncthreads();
    #pragma unroll
    for (int it = 0; it < 8; ++it) {
        int id = t + it * 256;
        int row = id >> 4, part = id & 15;
        *(s16x8*)&Cm[(size_t)(m0 + row) * ldc + n0 + part * 8] =
            *(const s16x8*)&El[row * 136 + part * 8];
    }
}

// ---------------------------------------------------------------- kernel 5
__global__ __launch_bounds__(512) void zeroL_k(float* __restrict__ L) {
    L[blockIdx.x * 512 + threadIdx.x] = 0.f;
}

// ---------------------------------------------------------------- kernel 6
// Ptil[slot][i][j] = exp2(SCL2 * sum_c q[i][c]k[j][c]); atomic row-sums into L[b][i].
__global__ __launch_bounds__(256, 4) void sgemm_k(const unsigned short* __restrict__ q_t,
                                                  const unsigned short* __restrict__ k_t,
                                                  unsigned short* __restrict__ Ptil,
                                                  float* __restrict__ L,
                                                  int bbase) {
    int z = blockIdx.z;
    int b = bbase + z;
    const unsigned short* A  = q_t + (size_t)b * N_ * C_;
    const unsigned short* Bm = k_t + (size_t)b * N_ * C_;
    unsigned short* Cm = Ptil + (size_t)z * N_ * N_;
    int m0 = blockIdx.y * 128, n0 = blockIdx.x * 128;

    __shared__ char smem[35072];
    unsigned short* Al = (unsigned short*)smem;
    unsigned short* Bl = Al + 8192;
    unsigned short* El = (unsigned short*)smem;

    int t = threadIdx.x;
    int wid = t >> 6, lane = t & 63;
    int wm = (wid >> 1) * 64, wn = (wid & 1) * 64;
    int lr = lane & 15, lg = lane >> 4;

    f32x4 acc[4][4] = {};
    gemm_core(A + (size_t)m0 * C_, C_, Bm + (size_t)n0 * C_, C_, Al, Bl, acc, C_ / 32, t);

    const float SCL2 = 0.06375862f;  // log2(e) / sqrt(512)
    float rsum[4][4];
    #pragma unroll
    for (int i = 0; i < 4; ++i)
        #pragma unroll
        for (int r = 0; r < 4; ++r) rsum[i][r] = 0.f;

    #pragma unroll
    for (int i = 0; i < 4; ++i)
        #pragma unroll
        for (int j = 0; j < 4; ++j) {
            int col = wn + j * 16 + lr;
            #pragma unroll
            for (int r = 0; r < 4; ++r) {
                float p = exp2f(acc[i][j][r] * SCL2);
                rsum[i][r] += p;
                El[(wm + i * 16 + lg * 4 + r) * 136 + col] = f2bf(p);
            }
        }
    #pragma unroll
    for (int msk = 8; msk >= 1; msk >>= 1)
        #pragma unroll
        for (int i = 0; i < 4; ++i)
            #pragma unroll
            for (int r = 0; r < 4; ++r)
                rsum[i][r] += __shfl_xor(rsum[i][r], msk);
    if (lr == 0) {
        #pragma unroll
        for (int i = 0; i < 4; ++i)
            #pragma unroll
            for (int r = 0; r < 4; ++r)
                atomicAdd(&L[(size_t)b * N_ + m0 + wm + i * 16 + lg * 4 + r], rsum[i][r]);
    }
    __syncthreads();
    #pragma unroll
    for (int it = 0; it < 8; ++it) {
        int id = t + it * 256;
        int row = id >> 4, part = id & 15;
        *(s16x8*)&Cm[(size_t)(m0 + row) * N_ + n0 + part * 8] =
            *(const s16x8*)&El[row * 136 + part * 8];
    }
}

// ---------------------------------------------------------------- kernel 7
// out[b][c][i] (+)= (sum_{j in K-range} v[c][j] * Ptil[slot][i][j]) / L[b][i]
// ATOMIC=false: full K, out = x + acc/L.  ATOMIC=true: out preinit to x, K split SK ways.
template <bool ATOMIC>
__global__ __launch_bounds__(256, 4) void pv_k(const unsigned short* __restrict__ vv,
                                               const unsigned short* __restrict__ Ptil,
                                               const float* __restrict__ L,
                                               const float* __restrict__ x,
                                               float* __restrict__ out,
                                               int bbase, int SK) {
    int z = blockIdx.z;
    int slot = z / SK, kr = z % SK;
    int b = bbase + slot;
    int kOff = kr * (N_ / SK);
    const unsigned short* A  = vv + (size_t)b * C_ * N_ + kOff;        // [c][j]
    const unsigned short* Bm = Ptil + (size_t)slot * N_ * N_ + kOff;   // [i][j]
    int m0 = blockIdx.y * 128, n0 = blockIdx.x * 128;
    const float* xb = x + (size_t)b * C_ * N_;
    float* ob = out + (size_t)b * C_ * N_;

    __shared__ char smem[32768];
    unsigned short* Al = (unsigned short*)smem;
    unsigned short* Bl = Al + 8192;

    int t = threadIdx.x;
    int wid = t >> 6, lane = t & 63;
    int wm = (wid >> 1) * 64, wn = (wid & 1) * 64;
    int lr = lane & 15, lg = lane >> 4;

    f32x4 acc[4][4] = {};
    gemm_core(A + (size_t)m0 * N_, N_, Bm + (size_t)n0 * N_, N_, Al, Bl, acc, (N_ / SK) / 32, t);

    #pragma unroll
    for (int j = 0; j < 4; ++j) {
        int col = n0 + wn + j * 16 + lr;
        float rl = 1.0f / L[(size_t)b * N_ + col];
        #pragma unroll
        for (int i = 0; i < 4; ++i) {
            #pragma unroll
            for (int r = 0; r < 4; ++r) {
                int row = m0 + wm + i * 16 + lg * 4 + r;
                size_t off = (size_t)row * N_ + col;
                if (ATOMIC) atomicAdd(&ob[off], acc[i][j][r] * rl);
                else        ob[off] = xb[off] + acc[i][j][r] * rl;
            }
        }
    }
}

// ---------------------------------------------------------------- launch
extern "C" void kernel_launch(void* const* d_in, const int* in_sizes, int n_in,
                              void* d_out, int out_size, void* d_ws, size_t ws_size,
                              hipStream_t stream) {
    const float* x   = (const float*)d_in[0];
    const float* gsc = (const float*)d_in[1];
    const float* gbi = (const float*)d_in[2];
    const float* wq  = (const float*)d_in[3];
    const float* bq  = (const float*)d_in[4];
    const float* wk  = (const float*)d_in[5];
    const float* bk  = (const float*)d_in[6];
    const float* wv  = (const float*)d_in[7];
    const float* bv  = (const float*)d_in[8];
    float* out = (float*)d_out;

    const size_t elems = (size_t)B_ * N_ * C_;   // 16.7M
    unsigned short* q_t   = (unsigned short*)d_ws;
    unsigned short* k_t   = q_t + elems;
    unsigned short* v     = k_t + elems;
    float*          stats = (float*)(v + elems);
    unsigned short* wbf   = (unsigned short*)(stats + 2 * B_ * G_);
    float*          L     = (float*)(wbf + (size_t)3 * C_ * C_);
    unsigned short* Ptil  = (unsigned short*)(L + (size_t)B_ * N_);
    unsigned short* h_t   = (unsigned short*)d_out;  // dead after qkv_k

    const size_t base_bytes = (size_t)((char*)Ptil - (char*)d_ws);
    const size_t slot_bytes = (size_t)N_ * N_ * 2;
    int slots = 2;
    if      (ws_size >= base_bytes + 8 * slot_bytes) slots = 8;
    else if (ws_size >= base_bytes + 4 * slot_bytes) slots = 4;
    const int SK = 8 / slots;   // pv z-dim = slots*SK = 8 always

    gn_stats_k<<<B_ * G_, 256, 0, stream>>>(x, stats);
    cvt_w_k<<<(3 * C_ * C_ / 4) / 256, 256, 0, stream>>>(wq, wk, wv, wbf);
    gn_apply_k<<<dim3(N_ / 64, C_ / 64, B_), 256, 0, stream>>>(x, stats, gsc, gbi, h_t);
    qkv_k<<<dim3(32, 4, 3 * B_), 256, 0, stream>>>(h_t, wbf, bq, bk, bv, q_t, k_t, v);
    zeroL_k<<<(B_ * N_) / 512, 512, 0, stream>>>(L);

    if (slots == 8) {
        sgemm_k<<<dim3(32, 32, 8), 256, 0, stream>>>(q_t, k_t, Ptil, L, 0);
        pv_k<false><<<dim3(32, 4, 8), 256, 0, stream>>>(v, Ptil, L, x, out, 0, 1);
    } else {
        copyx_k<<<2048, 256, 0, stream>>>(x, out);   // out = x; pv atomically adds
        for (int bb = 0; bb < B_; bb += slots) {
            sgemm_k<<<dim3(32, 32, slots), 256, 0, stream>>>(q_t, k_t, Ptil, L, bb);
            pv_k<true><<<dim3(32, 4, 8), 256, 0, stream>>>(v, Ptil, L, x, out, bb, SK);
        }
    }
}